// Round 10
// baseline (342.996 us; speedup 1.0000x reference)
//
#include <hip/hip_runtime.h>
#include <math.h>
#include <stddef.h>

#define BB 4
#define LL 1024
#define DM 512
#define ED 1024
#define NST 16
#define DTR 32
#define XDBC 64
#define BL (BB*LL)   // 4096
#define CS 32        // scan chunk length
#define NC 32        // chunks per sequence (LL/CS)
#define LDSK 40      // padded LDS k-stride (ushorts) for bf16 GEMM
#define XKS 16       // x_proj K-slices
#define XPAD 68      // x_proj LDS stride (floats)

typedef __attribute__((ext_vector_type(8))) short bf16x8;
typedef __attribute__((ext_vector_type(4))) float f32x4;
typedef unsigned short ushort_t;

__device__ __forceinline__ float silu_f(float x) { return x / (1.f + __expf(-x)); }

// fp32 <-> bf16
__device__ __forceinline__ ushort_t f2b(float f) {
    unsigned int u = __float_as_uint(f);
    unsigned int r = (u + 0x7FFFu + ((u >> 16) & 1u)) >> 16;
    return (ushort_t)r;
}
__device__ __forceinline__ float b2f(ushort_t v) {
    return __uint_as_float(((unsigned int)v) << 16);
}

// ---------------- embedding
__global__ void k_embed(const float* __restrict__ x, const float* __restrict__ W,
                        const float* __restrict__ bias, float* __restrict__ h) {
    int i = blockIdx.x * 256 + threadIdx.x;
    if (i >= BL * DM) return;
    int d = i % DM, r = i / DM;
    h[i] = x[r * 2 + 0] * W[d * 2 + 0] + x[r * 2 + 1] * W[d * 2 + 1] + bias[d];
}

// ---------------- fp32 -> bf16 bulk convert
__global__ void k_cvt(const float* __restrict__ in, ushort_t* __restrict__ out, int n4) {
    int i = blockIdx.x * 256 + threadIdx.x;
    if (i >= n4) return;
    float4 v = *(const float4*)(in + (size_t)i * 4);
    ushort_t o[4] = {f2b(v.x), f2b(v.y), f2b(v.z), f2b(v.w)};
    *(uint2*)(out + (size_t)i * 4) = *(uint2*)o;
}

// ---------------- rmsnorm over rows of 512; BF16OUT selects output dtype
template <int BF16OUT>
__global__ __launch_bounds__(256) void k_rmsnorm(const float* __restrict__ in,
                                                 const float* __restrict__ w,
                                                 void* __restrict__ outp) {
    int m = blockIdx.x;
    int tid = threadIdx.x;
    const float* row = in + (size_t)m * DM;
    float2 v = *(const float2*)(row + tid * 2);
    float ss = v.x * v.x + v.y * v.y;
    #pragma unroll
    for (int o = 32; o > 0; o >>= 1) ss += __shfl_down(ss, o, 64);
    __shared__ float red[4];
    int wid = tid >> 6;
    if ((tid & 63) == 0) red[wid] = ss;
    __syncthreads();
    float tot = red[0] + red[1] + red[2] + red[3];
    float rs = rsqrtf(tot * (1.f / DM) + 1e-5f);
    float2 wv = *(const float2*)(w + tid * 2);
    float ox = v.x * rs * wv.x;
    float oy = v.y * rs * wv.y;
    if (BF16OUT) {
        ushort_t o[2] = {f2b(ox), f2b(oy)};
        *(unsigned int*)((ushort_t*)outp + (size_t)m * DM + tid * 2) = *(unsigned int*)o;
    } else {
        *(float2*)((float*)outp + (size_t)m * DM + tid * 2) = make_float2(ox, oy);
    }
}

// ---------------- bf16 MFMA GEMM: C[m,n] = (ADD?Res:0) + sum_k A[m,k]*W[n,k]
// BF16OUT: C is bf16 (no Res); else C fp32 (optional Res add).
template <int ADDRES, int BF16OUT>
__global__ __launch_bounds__(256) void k_bgemm(const ushort_t* __restrict__ A,
                                               const ushort_t* __restrict__ W,
                                               const float* __restrict__ Res,
                                               void* __restrict__ C,
                                               int M, int N, int K, int lda, int ldc) {
    __shared__ ushort_t As[128 * LDSK];
    __shared__ ushort_t Bs[128 * LDSK];
    int tid = threadIdx.x;
    int bm = blockIdx.y * 128, bn = blockIdx.x * 128;
    int wave = tid >> 6, lane = tid & 63;
    int wr = wave >> 1, wc = wave & 1;       // 2x2 wave grid, 64x64 each
    int lr = lane & 15, lk = (lane >> 4) * 8;
    int srow = tid >> 2;                     // staging: 0..63
    int skb = (tid & 3) * 8;                 // k-chunk 0,8,16,24
    f32x4 acc[4][4];
    #pragma unroll
    for (int i = 0; i < 4; ++i)
        #pragma unroll
        for (int j = 0; j < 4; ++j) acc[i][j] = (f32x4){0.f, 0.f, 0.f, 0.f};

    for (int k0 = 0; k0 < K; k0 += 32) {
        uint4 a0 = *(const uint4*)(A + (size_t)(bm + srow) * lda + k0 + skb);
        uint4 a1 = *(const uint4*)(A + (size_t)(bm + 64 + srow) * lda + k0 + skb);
        uint4 b0 = *(const uint4*)(W + (size_t)(bn + srow) * K + k0 + skb);
        uint4 b1 = *(const uint4*)(W + (size_t)(bn + 64 + srow) * K + k0 + skb);
        __syncthreads();
        *(uint4*)(As + srow * LDSK + skb) = a0;
        *(uint4*)(As + (64 + srow) * LDSK + skb) = a1;
        *(uint4*)(Bs + srow * LDSK + skb) = b0;
        *(uint4*)(Bs + (64 + srow) * LDSK + skb) = b1;
        __syncthreads();
        bf16x8 af[4], bfr[4];
        #pragma unroll
        for (int i = 0; i < 4; ++i)
            af[i] = *(const bf16x8*)(As + (wr * 64 + i * 16 + lr) * LDSK + lk);
        #pragma unroll
        for (int j = 0; j < 4; ++j)
            bfr[j] = *(const bf16x8*)(Bs + (wc * 64 + j * 16 + lr) * LDSK + lk);
        #pragma unroll
        for (int i = 0; i < 4; ++i)
            #pragma unroll
            for (int j = 0; j < 4; ++j)
                acc[i][j] = __builtin_amdgcn_mfma_f32_16x16x32_bf16(af[i], bfr[j], acc[i][j], 0, 0, 0);
    }
    int crow0 = bm + wr * 64 + (lane >> 4) * 4;
    int ccol0 = bn + wc * 64 + lr;
    #pragma unroll
    for (int i = 0; i < 4; ++i)
        #pragma unroll
        for (int j = 0; j < 4; ++j)
            #pragma unroll
            for (int r = 0; r < 4; ++r) {
                size_t off = (size_t)(crow0 + i * 16 + r) * ldc + ccol0 + j * 16;
                float v = acc[i][j][r];
                if (ADDRES) v += Res[off];
                if (BF16OUT) ((ushort_t*)C)[off] = f2b(v);
                else         ((float*)C)[off] = v;
            }
}

// ---------------- x_proj split-K
__global__ __launch_bounds__(256) void k_xproj(const float* __restrict__ A,
                                               const float* __restrict__ W,
                                               float* __restrict__ Pp) {
    __shared__ float As[64][XPAD];
    __shared__ float Ws[64][XPAD];
    int tid = threadIdx.x;
    int k0 = blockIdx.x * 64;
    int bm = blockIdx.y * 64;
    int r = tid >> 2;            // 0..63
    int kc = (tid & 3) * 16;     // 0,16,32,48
    const float4* ap = (const float4*)(A + (size_t)(bm + r) * ED + k0 + kc);
    const float4* wp = (const float4*)(W + (size_t)r * ED + k0 + kc);
    #pragma unroll
    for (int i = 0; i < 4; ++i) {
        float4 av = ap[i];
        float4 wv = wp[i];
        As[kc + i * 4 + 0][r] = av.x; As[kc + i * 4 + 1][r] = av.y;
        As[kc + i * 4 + 2][r] = av.z; As[kc + i * 4 + 3][r] = av.w;
        Ws[kc + i * 4 + 0][r] = wv.x; Ws[kc + i * 4 + 1][r] = wv.y;
        Ws[kc + i * 4 + 2][r] = wv.z; Ws[kc + i * 4 + 3][r] = wv.w;
    }
    __syncthreads();
    int tm = (tid >> 4) * 4;
    int tn = (tid & 15) * 4;
    float acc[4][4] = {};
    #pragma unroll 4
    for (int k = 0; k < 64; ++k) {
        float4 a = *(const float4*)&As[k][tm];
        float4 b = *(const float4*)&Ws[k][tn];
        acc[0][0] += a.x * b.x; acc[0][1] += a.x * b.y; acc[0][2] += a.x * b.z; acc[0][3] += a.x * b.w;
        acc[1][0] += a.y * b.x; acc[1][1] += a.y * b.y; acc[1][2] += a.y * b.z; acc[1][3] += a.y * b.w;
        acc[2][0] += a.z * b.x; acc[2][1] += a.z * b.y; acc[2][2] += a.z * b.z; acc[2][3] += a.z * b.w;
        acc[3][0] += a.w * b.x; acc[3][1] += a.w * b.y; acc[3][2] += a.w * b.z; acc[3][3] += a.w * b.w;
    }
    float* pp = Pp + (size_t)blockIdx.x * BL * XDBC;
    #pragma unroll
    for (int i = 0; i < 4; ++i)
        *(float4*)(pp + (size_t)(bm + tm + i) * XDBC + tn) =
            make_float4(acc[i][0], acc[i][1], acc[i][2], acc[i][3]);
}

// reduce 16 K-slice partials -> xdb
__global__ void k_xred(const float* __restrict__ Pp, float* __restrict__ xdb) {
    int i = blockIdx.x * 256 + threadIdx.x;
    float4 s = make_float4(0.f, 0.f, 0.f, 0.f);
    #pragma unroll
    for (int sl = 0; sl < XKS; ++sl) {
        float4 v = *(const float4*)(Pp + (size_t)sl * BL * XDBC + (size_t)i * 4);
        s.x += v.x; s.y += v.y; s.z += v.z; s.w += v.w;
    }
    *(float4*)(xdb + (size_t)i * 4) = s;
}

// ---------------- causal depthwise conv (k=4) + bias + silu; bf16 xz input
__global__ void k_conv(const ushort_t* __restrict__ xzb, const float* __restrict__ cw,
                       const float* __restrict__ cb, float* __restrict__ u) {
    int i = blockIdx.x * 256 + threadIdx.x;
    if (i >= BL * ED) return;
    int e = i % ED;
    int t = (i / ED) % LL;
    int b = i / (ED * LL);
    const ushort_t* col = xzb + (size_t)b * LL * 2048 + e;
    float4 w4 = *(const float4*)(cw + e * 4);
    float acc = cb[e];
    if (t >= 3) acc += b2f(col[(size_t)(t - 3) * 2048]) * w4.x;
    if (t >= 2) acc += b2f(col[(size_t)(t - 2) * 2048]) * w4.y;
    if (t >= 1) acc += b2f(col[(size_t)(t - 1) * 2048]) * w4.z;
    acc += b2f(col[(size_t)t * 2048]) * w4.w;
    u[i] = silu_f(acc);
}

// ================ chunked selective scan (delta fused inline) ================
// delta[t][e] = softplus(xdb[t][0:32] . dtW[e] + dtb[e]) computed on the fly.
__global__ __launch_bounds__(256) void k_scan1(const float* __restrict__ xdb,
                                               const float* __restrict__ u,
                                               const float* __restrict__ dtW,
                                               const float* __restrict__ dtb,
                                               const float* __restrict__ A_log,
                                               float* __restrict__ P,
                                               float* __restrict__ S) {
    int tid = threadIdx.x;
    int e = ((blockIdx.x & 3) << 8) + tid;
    int c = (blockIdx.x >> 2) & (NC - 1);
    int b = blockIdx.x >> 7;
    float Ac[16], dtw[32];
    const float4* ap = (const float4*)(A_log + (size_t)e * NST);
    #pragma unroll
    for (int q = 0; q < 4; ++q) {
        float4 a = ap[q];
        Ac[q * 4 + 0] = -__expf(a.x); Ac[q * 4 + 1] = -__expf(a.y);
        Ac[q * 4 + 2] = -__expf(a.z); Ac[q * 4 + 3] = -__expf(a.w);
    }
    const float4* wq = (const float4*)(dtW + (size_t)e * DTR);
    #pragma unroll
    for (int q = 0; q < 8; ++q) {
        float4 w = wq[q];
        dtw[q * 4 + 0] = w.x; dtw[q * 4 + 1] = w.y;
        dtw[q * 4 + 2] = w.z; dtw[q * 4 + 3] = w.w;
    }
    float bias = dtb[e];
    float h[16] = {};
    float s = 0.f;
    const float* up = u + ((size_t)b * LL + c * CS) * ED + e;
    const float* xp = xdb + ((size_t)b * LL + c * CS) * XDBC;
    for (int tt = 0; tt < CS; ++tt) {
        const float4* dr = (const float4*)(xp + tt * XDBC);
        float acc = bias;
        #pragma unroll
        for (int q = 0; q < 8; ++q) {
            float4 d = dr[q];
            acc += d.x * dtw[q * 4 + 0] + d.y * dtw[q * 4 + 1] +
                   d.z * dtw[q * 4 + 2] + d.w * dtw[q * 4 + 3];
        }
        float dv = (acc > 20.f) ? acc : __logf(1.f + __expf(acc));
        float uv = up[(size_t)tt * ED];
        s += dv;
        float du = dv * uv;
        #pragma unroll
        for (int q = 0; q < 4; ++q) {
            float4 bv = dr[8 + q];
            h[q * 4 + 0] = __expf(dv * Ac[q * 4 + 0]) * h[q * 4 + 0] + du * bv.x;
            h[q * 4 + 1] = __expf(dv * Ac[q * 4 + 1]) * h[q * 4 + 1] + du * bv.y;
            h[q * 4 + 2] = __expf(dv * Ac[q * 4 + 2]) * h[q * 4 + 2] + du * bv.z;
            h[q * 4 + 3] = __expf(dv * Ac[q * 4 + 3]) * h[q * 4 + 3] + du * bv.w;
        }
    }
    float4* pp = (float4*)(P + ((size_t)(b * NC + c) * ED + e) * NST);
    pp[0] = make_float4(h[0], h[1], h[2], h[3]);
    pp[1] = make_float4(h[4], h[5], h[6], h[7]);
    pp[2] = make_float4(h[8], h[9], h[10], h[11]);
    pp[3] = make_float4(h[12], h[13], h[14], h[15]);
    S[(size_t)(b * NC + c) * ED + e] = s;
}

__global__ __launch_bounds__(256) void k_scan2(float* __restrict__ P,
                                               const float* __restrict__ S,
                                               const float* __restrict__ A_log) {
    int i = blockIdx.x * 256 + threadIdx.x;
    int n = i & 15;
    int e = (i >> 4) & (ED - 1);
    int b = i >> 14;
    float Ac = -__expf(A_log[(size_t)e * NST + n]);
    float hin = 0.f;
    for (int c = 0; c < NC; ++c) {
        size_t base = (size_t)(b * NC + c) * ED + e;
        float p = P[base * NST + n];
        float s = S[base];
        P[base * NST + n] = hin;
        hin = __expf(Ac * s) * hin + p;
    }
}

// Pass 3: re-scan with correct h_in; inline delta; fused silu(z) gate (bf16 z);
// emits bf16 yb for the out_proj MFMA GEMM.
__global__ __launch_bounds__(256) void k_scan3(const float* __restrict__ xdb,
                                               const float* __restrict__ u,
                                               const ushort_t* __restrict__ xzb,
                                               const float* __restrict__ dtW,
                                               const float* __restrict__ dtb,
                                               const float* __restrict__ A_log,
                                               const float* __restrict__ Dskip,
                                               const float* __restrict__ P,
                                               ushort_t* __restrict__ yb) {
    int tid = threadIdx.x;
    int e = ((blockIdx.x & 3) << 8) + tid;
    int c = (blockIdx.x >> 2) & (NC - 1);
    int b = blockIdx.x >> 7;
    float Ac[16], dtw[32], h[16];
    const float4* ap = (const float4*)(A_log + (size_t)e * NST);
    #pragma unroll
    for (int q = 0; q < 4; ++q) {
        float4 a = ap[q];
        Ac[q * 4 + 0] = -__expf(a.x); Ac[q * 4 + 1] = -__expf(a.y);
        Ac[q * 4 + 2] = -__expf(a.z); Ac[q * 4 + 3] = -__expf(a.w);
    }
    const float4* wq = (const float4*)(dtW + (size_t)e * DTR);
    #pragma unroll
    for (int q = 0; q < 8; ++q) {
        float4 w = wq[q];
        dtw[q * 4 + 0] = w.x; dtw[q * 4 + 1] = w.y;
        dtw[q * 4 + 2] = w.z; dtw[q * 4 + 3] = w.w;
    }
    float bias = dtb[e];
    const float4* pp = (const float4*)(P + ((size_t)(b * NC + c) * ED + e) * NST);
    #pragma unroll
    for (int q = 0; q < 4; ++q) {
        float4 hv = pp[q];
        h[q * 4 + 0] = hv.x; h[q * 4 + 1] = hv.y;
        h[q * 4 + 2] = hv.z; h[q * 4 + 3] = hv.w;
    }
    float Dk = Dskip[e];
    const float* up = u + ((size_t)b * LL + c * CS) * ED + e;
    const float* xp = xdb + ((size_t)b * LL + c * CS) * XDBC;
    const ushort_t* zp = xzb + ((size_t)b * LL + c * CS) * 2048 + 1024 + e;
    ushort_t* yp = yb + ((size_t)b * LL + c * CS) * ED + e;
    for (int tt = 0; tt < CS; ++tt) {
        const float4* dr = (const float4*)(xp + tt * XDBC);
        float acc = bias;
        #pragma unroll
        for (int q = 0; q < 8; ++q) {
            float4 d = dr[q];
            acc += d.x * dtw[q * 4 + 0] + d.y * dtw[q * 4 + 1] +
                   d.z * dtw[q * 4 + 2] + d.w * dtw[q * 4 + 3];
        }
        float dv = (acc > 20.f) ? acc : __logf(1.f + __expf(acc));
        float uv = up[(size_t)tt * ED];
        float zv = b2f(zp[(size_t)tt * 2048]);
        float du = dv * uv;
        float y = 0.f;
        #pragma unroll
        for (int q = 0; q < 4; ++q) {
            float4 bv = dr[8 + q];
            float4 cv = dr[12 + q];
            h[q * 4 + 0] = __expf(dv * Ac[q * 4 + 0]) * h[q * 4 + 0] + du * bv.x;
            h[q * 4 + 1] = __expf(dv * Ac[q * 4 + 1]) * h[q * 4 + 1] + du * bv.y;
            h[q * 4 + 2] = __expf(dv * Ac[q * 4 + 2]) * h[q * 4 + 2] + du * bv.z;
            h[q * 4 + 3] = __expf(dv * Ac[q * 4 + 3]) * h[q * 4 + 3] + du * bv.w;
            y += h[q * 4 + 0] * cv.x + h[q * 4 + 1] * cv.y +
                 h[q * 4 + 2] * cv.z + h[q * 4 + 3] * cv.w;
        }
        yp[(size_t)tt * ED] = f2b((y + Dk * uv) * silu_f(zv));
    }
}

extern "C" void kernel_launch(void* const* d_in, const int* in_sizes, int n_in,
                              void* d_out, int out_size, void* d_ws, size_t ws_size,
                              hipStream_t stream) {
    const float* x     = (const float*)d_in[0];
    const float* embW  = (const float*)d_in[1];
    const float* embB  = (const float*)d_in[2];
    const float* normw = (const float*)d_in[3];
    const float* ipW   = (const float*)d_in[4];
    const float* cW    = (const float*)d_in[5];
    const float* cb    = (const float*)d_in[6];
    const float* xpW   = (const float*)d_in[7];
    const float* dtW   = (const float*)d_in[8];
    const float* dtb   = (const float*)d_in[9];
    const float* Alog  = (const float*)d_in[10];
    const float* Dsk   = (const float*)d_in[11];
    const float* opW   = (const float*)d_in[12];
    const float* normfw= (const float*)d_in[13];
    float* out = (float*)d_out;

    // ws layout: h 8MB | xzb(bf16) 16MB | u 16MB | xdb 1MB | Pp 16MB | S 0.5MB
    //            | wip(both layers) 4MB | wop 2MB | yb 8MB  ~= 71.5 MB
    float* ws  = (float*)d_ws;
    float* h   = ws;
    ushort_t* xzb = (ushort_t*)(h + (size_t)BL * DM);
    float* u   = (float*)(xzb + (size_t)BL * 2 * ED);
    float* xdb = u + (size_t)BL * ED;
    float* Pp  = xdb + (size_t)BL * XDBC;
    float* S   = Pp + (size_t)BL * ED;
    ushort_t* wip = (ushort_t*)(S + (size_t)BB * NC * ED);  // 2 layers in_proj
    ushort_t* wop = wip + (size_t)2 * 2 * ED * DM;          // 2 layers out_proj
    ushort_t* yb  = wop + (size_t)2 * DM * ED;
    ushort_t* hnb = (ushort_t*)d_out;  // bf16 rmsnorm scratch (d_out reuse)
    float* P      = out;               // chunk-state buffer (d_out reuse)

    k_embed<<<(BL * DM + 255) / 256, 256, 0, stream>>>(x, embW, embB, h);
    // convert ALL layer weights once (ipW: 2*2048*512, opW: 2*512*1024 floats)
    k_cvt<<<(2 * 2 * ED * DM / 4 + 255) / 256, 256, 0, stream>>>(ipW, wip, 2 * 2 * ED * DM / 4);
    k_cvt<<<(2 * DM * ED / 4 + 255) / 256, 256, 0, stream>>>(opW, wop, 2 * DM * ED / 4);

    for (int l = 0; l < 2; ++l) {
        const float* Al = Alog + (size_t)l * ED * NST;
        const float* dtWl = dtW + (size_t)l * ED * DTR;
        const float* dtbl = dtb + (size_t)l * ED;
        k_rmsnorm<1><<<BL, 256, 0, stream>>>(h, normw + (size_t)l * DM, hnb);
        k_bgemm<0, 1><<<dim3(2 * ED / 128, BL / 128), 256, 0, stream>>>(
            hnb, wip + (size_t)l * 2 * ED * DM, nullptr, xzb, BL, 2 * ED, DM, DM, 2 * ED);
        k_conv<<<(BL * ED + 255) / 256, 256, 0, stream>>>(
            xzb, cW + (size_t)l * ED * 4, cb + (size_t)l * ED, u);
        k_xproj<<<dim3(XKS, BL / 64), 256, 0, stream>>>(
            u, xpW + (size_t)l * XDBC * ED, Pp);
        k_xred<<<BL * XDBC / 4 / 256, 256, 0, stream>>>(Pp, xdb);
        k_scan1<<<BB * NC * (ED / 256), 256, 0, stream>>>(xdb, u, dtWl, dtbl, Al, P, S);
        k_scan2<<<BB * ED * NST / 256, 256, 0, stream>>>(P, S, Al);
        k_scan3<<<BB * NC * (ED / 256), 256, 0, stream>>>(
            xdb, u, xzb, dtWl, dtbl, Al, Dsk + (size_t)l * ED, P, yb);
        k_bgemm<1, 0><<<dim3(DM / 128, BL / 128), 256, 0, stream>>>(
            yb, wop + (size_t)l * DM * ED, h, h, BL, DM, ED, ED, DM);
    }
    k_rmsnorm<0><<<BL, 256, 0, stream>>>(h, normfw, out);
}

// Round 11
// 299.407 us; speedup vs baseline: 1.1456x; 1.1456x over previous
//
#include <hip/hip_runtime.h>
#include <math.h>
#include <stddef.h>

#define BB 4
#define LL 1024
#define DM 512
#define ED 1024
#define NST 16
#define DTR 32
#define XDBC 64
#define BL (BB*LL)   // 4096
#define CS 16        // scan chunk length
#define NC 64        // chunks per sequence (LL/CS)
#define LDSK 40      // padded LDS k-stride (ushorts) for bf16 GEMM
#define XKS 16       // x_proj K-slices
#define XPAD 68      // x_proj LDS stride (floats)
#define DPAD 132     // k_delta LDS stride (floats)

typedef __attribute__((ext_vector_type(8))) short bf16x8;
typedef __attribute__((ext_vector_type(4))) float f32x4;
typedef unsigned short ushort_t;

__device__ __forceinline__ float silu_f(float x) { return x / (1.f + __expf(-x)); }

// fp32 <-> bf16
__device__ __forceinline__ ushort_t f2b(float f) {
    unsigned int u = __float_as_uint(f);
    unsigned int r = (u + 0x7FFFu + ((u >> 16) & 1u)) >> 16;
    return (ushort_t)r;
}
__device__ __forceinline__ float b2f(ushort_t v) {
    return __uint_as_float(((unsigned int)v) << 16);
}
// fp32 <-> fp16 (for the delta buffer; softplus output <= ~20, fp16-safe)
__device__ __forceinline__ ushort_t f2h(float f) {
    _Float16 h = (_Float16)f;
    return *(ushort_t*)&h;
}
__device__ __forceinline__ float h2f(ushort_t v) {
    _Float16 h = *(_Float16*)&v;
    return (float)h;
}

// ---------------- embedding
__global__ void k_embed(const float* __restrict__ x, const float* __restrict__ W,
                        const float* __restrict__ bias, float* __restrict__ h) {
    int i = blockIdx.x * 256 + threadIdx.x;
    if (i >= BL * DM) return;
    int d = i % DM, r = i / DM;
    h[i] = x[r * 2 + 0] * W[d * 2 + 0] + x[r * 2 + 1] * W[d * 2 + 1] + bias[d];
}

// ---------------- fp32 -> bf16 bulk convert
__global__ void k_cvt(const float* __restrict__ in, ushort_t* __restrict__ out, int n4) {
    int i = blockIdx.x * 256 + threadIdx.x;
    if (i >= n4) return;
    float4 v = *(const float4*)(in + (size_t)i * 4);
    ushort_t o[4] = {f2b(v.x), f2b(v.y), f2b(v.z), f2b(v.w)};
    *(uint2*)(out + (size_t)i * 4) = *(uint2*)o;
}

// ---------------- rmsnorm over rows of 512; BF16OUT selects output dtype
template <int BF16OUT>
__global__ __launch_bounds__(256) void k_rmsnorm(const float* __restrict__ in,
                                                 const float* __restrict__ w,
                                                 void* __restrict__ outp) {
    int m = blockIdx.x;
    int tid = threadIdx.x;
    const float* row = in + (size_t)m * DM;
    float2 v = *(const float2*)(row + tid * 2);
    float ss = v.x * v.x + v.y * v.y;
    #pragma unroll
    for (int o = 32; o > 0; o >>= 1) ss += __shfl_down(ss, o, 64);
    __shared__ float red[4];
    int wid = tid >> 6;
    if ((tid & 63) == 0) red[wid] = ss;
    __syncthreads();
    float tot = red[0] + red[1] + red[2] + red[3];
    float rs = rsqrtf(tot * (1.f / DM) + 1e-5f);
    float2 wv = *(const float2*)(w + tid * 2);
    float ox = v.x * rs * wv.x;
    float oy = v.y * rs * wv.y;
    if (BF16OUT) {
        ushort_t o[2] = {f2b(ox), f2b(oy)};
        *(unsigned int*)((ushort_t*)outp + (size_t)m * DM + tid * 2) = *(unsigned int*)o;
    } else {
        *(float2*)((float*)outp + (size_t)m * DM + tid * 2) = make_float2(ox, oy);
    }
}

// ---------------- bf16 MFMA GEMM: C[m,n] = (ADD?Res:0) + sum_k A[m,k]*W[n,k]
template <int ADDRES, int BF16OUT>
__global__ __launch_bounds__(256) void k_bgemm(const ushort_t* __restrict__ A,
                                               const ushort_t* __restrict__ W,
                                               const float* __restrict__ Res,
                                               void* __restrict__ C,
                                               int M, int N, int K, int lda, int ldc) {
    __shared__ ushort_t As[128 * LDSK];
    __shared__ ushort_t Bs[128 * LDSK];
    int tid = threadIdx.x;
    int bm = blockIdx.y * 128, bn = blockIdx.x * 128;
    int wave = tid >> 6, lane = tid & 63;
    int wr = wave >> 1, wc = wave & 1;
    int lr = lane & 15, lk = (lane >> 4) * 8;
    int srow = tid >> 2;
    int skb = (tid & 3) * 8;
    f32x4 acc[4][4];
    #pragma unroll
    for (int i = 0; i < 4; ++i)
        #pragma unroll
        for (int j = 0; j < 4; ++j) acc[i][j] = (f32x4){0.f, 0.f, 0.f, 0.f};

    for (int k0 = 0; k0 < K; k0 += 32) {
        uint4 a0 = *(const uint4*)(A + (size_t)(bm + srow) * lda + k0 + skb);
        uint4 a1 = *(const uint4*)(A + (size_t)(bm + 64 + srow) * lda + k0 + skb);
        uint4 b0 = *(const uint4*)(W + (size_t)(bn + srow) * K + k0 + skb);
        uint4 b1 = *(const uint4*)(W + (size_t)(bn + 64 + srow) * K + k0 + skb);
        __syncthreads();
        *(uint4*)(As + srow * LDSK + skb) = a0;
        *(uint4*)(As + (64 + srow) * LDSK + skb) = a1;
        *(uint4*)(Bs + srow * LDSK + skb) = b0;
        *(uint4*)(Bs + (64 + srow) * LDSK + skb) = b1;
        __syncthreads();
        bf16x8 af[4], bfr[4];
        #pragma unroll
        for (int i = 0; i < 4; ++i)
            af[i] = *(const bf16x8*)(As + (wr * 64 + i * 16 + lr) * LDSK + lk);
        #pragma unroll
        for (int j = 0; j < 4; ++j)
            bfr[j] = *(const bf16x8*)(Bs + (wc * 64 + j * 16 + lr) * LDSK + lk);
        #pragma unroll
        for (int i = 0; i < 4; ++i)
            #pragma unroll
            for (int j = 0; j < 4; ++j)
                acc[i][j] = __builtin_amdgcn_mfma_f32_16x16x32_bf16(af[i], bfr[j], acc[i][j], 0, 0, 0);
    }
    int crow0 = bm + wr * 64 + (lane >> 4) * 4;
    int ccol0 = bn + wc * 64 + lr;
    #pragma unroll
    for (int i = 0; i < 4; ++i)
        #pragma unroll
        for (int j = 0; j < 4; ++j)
            #pragma unroll
            for (int r = 0; r < 4; ++r) {
                size_t off = (size_t)(crow0 + i * 16 + r) * ldc + ccol0 + j * 16;
                float v = acc[i][j][r];
                if (ADDRES) v += Res[off];
                if (BF16OUT) ((ushort_t*)C)[off] = f2b(v);
                else         ((float*)C)[off] = v;
            }
}

// ---------------- x_proj split-K
__global__ __launch_bounds__(256) void k_xproj(const float* __restrict__ A,
                                               const float* __restrict__ W,
                                               float* __restrict__ Pp) {
    __shared__ float As[64][XPAD];
    __shared__ float Ws[64][XPAD];
    int tid = threadIdx.x;
    int k0 = blockIdx.x * 64;
    int bm = blockIdx.y * 64;
    int r = tid >> 2;
    int kc = (tid & 3) * 16;
    const float4* ap = (const float4*)(A + (size_t)(bm + r) * ED + k0 + kc);
    const float4* wp = (const float4*)(W + (size_t)r * ED + k0 + kc);
    #pragma unroll
    for (int i = 0; i < 4; ++i) {
        float4 av = ap[i];
        float4 wv = wp[i];
        As[kc + i * 4 + 0][r] = av.x; As[kc + i * 4 + 1][r] = av.y;
        As[kc + i * 4 + 2][r] = av.z; As[kc + i * 4 + 3][r] = av.w;
        Ws[kc + i * 4 + 0][r] = wv.x; Ws[kc + i * 4 + 1][r] = wv.y;
        Ws[kc + i * 4 + 2][r] = wv.z; Ws[kc + i * 4 + 3][r] = wv.w;
    }
    __syncthreads();
    int tm = (tid >> 4) * 4;
    int tn = (tid & 15) * 4;
    float acc[4][4] = {};
    #pragma unroll 4
    for (int k = 0; k < 64; ++k) {
        float4 a = *(const float4*)&As[k][tm];
        float4 b = *(const float4*)&Ws[k][tn];
        acc[0][0] += a.x * b.x; acc[0][1] += a.x * b.y; acc[0][2] += a.x * b.z; acc[0][3] += a.x * b.w;
        acc[1][0] += a.y * b.x; acc[1][1] += a.y * b.y; acc[1][2] += a.y * b.z; acc[1][3] += a.y * b.w;
        acc[2][0] += a.z * b.x; acc[2][1] += a.z * b.y; acc[2][2] += a.z * b.z; acc[2][3] += a.z * b.w;
        acc[3][0] += a.w * b.x; acc[3][1] += a.w * b.y; acc[3][2] += a.w * b.z; acc[3][3] += a.w * b.w;
    }
    float* pp = Pp + (size_t)blockIdx.x * BL * XDBC;
    #pragma unroll
    for (int i = 0; i < 4; ++i)
        *(float4*)(pp + (size_t)(bm + tm + i) * XDBC + tn) =
            make_float4(acc[i][0], acc[i][1], acc[i][2], acc[i][3]);
}

// reduce 16 K-slice partials -> xdb
__global__ void k_xred(const float* __restrict__ Pp, float* __restrict__ xdb) {
    int i = blockIdx.x * 256 + threadIdx.x;
    float4 s = make_float4(0.f, 0.f, 0.f, 0.f);
    #pragma unroll
    for (int sl = 0; sl < XKS; ++sl) {
        float4 v = *(const float4*)(Pp + (size_t)sl * BL * XDBC + (size_t)i * 4);
        s.x += v.x; s.y += v.y; s.z += v.z; s.w += v.w;
    }
    *(float4*)(xdb + (size_t)i * 4) = s;
}

// ---------------- causal depthwise conv (k=4) + bias + silu; bf16 xz input
__global__ void k_conv(const ushort_t* __restrict__ xzb, const float* __restrict__ cw,
                       const float* __restrict__ cb, float* __restrict__ u) {
    int i = blockIdx.x * 256 + threadIdx.x;
    if (i >= BL * ED) return;
    int e = i % ED;
    int t = (i / ED) % LL;
    int b = i / (ED * LL);
    const ushort_t* col = xzb + (size_t)b * LL * 2048 + e;
    float4 w4 = *(const float4*)(cw + e * 4);
    float acc = cb[e];
    if (t >= 3) acc += b2f(col[(size_t)(t - 3) * 2048]) * w4.x;
    if (t >= 2) acc += b2f(col[(size_t)(t - 2) * 2048]) * w4.y;
    if (t >= 1) acc += b2f(col[(size_t)(t - 1) * 2048]) * w4.z;
    acc += b2f(col[(size_t)t * 2048]) * w4.w;
    u[i] = silu_f(acc);
}

// ---------------- delta = softplus(dt @ dtW^T + dtb), tiled; fp16 output
__global__ __launch_bounds__(256) void k_delta(const float* __restrict__ xdb,
                                               const float* __restrict__ dtW,
                                               const float* __restrict__ dtb,
                                               ushort_t* __restrict__ dyh) {
    __shared__ float Dt[32][DPAD];   // [k][m-row]
    __shared__ float Wt[32][DPAD];   // [k][e-col]
    int tid = threadIdx.x;
    int bm = blockIdx.y * 128;
    int bn = blockIdx.x * 128;
    int r = tid >> 1;
    int hh = (tid & 1) * 16;
    const float4* dp = (const float4*)(xdb + (size_t)(bm + r) * XDBC + hh);
    const float4* wp = (const float4*)(dtW + (size_t)(bn + r) * 32 + hh);
    #pragma unroll
    for (int i = 0; i < 4; ++i) {
        float4 v = dp[i];
        Dt[hh + i * 4 + 0][r] = v.x; Dt[hh + i * 4 + 1][r] = v.y;
        Dt[hh + i * 4 + 2][r] = v.z; Dt[hh + i * 4 + 3][r] = v.w;
        float4 w = wp[i];
        Wt[hh + i * 4 + 0][r] = w.x; Wt[hh + i * 4 + 1][r] = w.y;
        Wt[hh + i * 4 + 2][r] = w.z; Wt[hh + i * 4 + 3][r] = w.w;
    }
    __syncthreads();
    int tm = (tid >> 4) * 8;
    int tn = (tid & 15) * 8;
    float acc[8][8] = {};
    #pragma unroll 8
    for (int k = 0; k < 32; ++k) {
        float4 a0 = *(const float4*)&Dt[k][tm];
        float4 a1 = *(const float4*)&Dt[k][tm + 4];
        float4 b0 = *(const float4*)&Wt[k][tn];
        float4 b1 = *(const float4*)&Wt[k][tn + 4];
        float a[8] = {a0.x, a0.y, a0.z, a0.w, a1.x, a1.y, a1.z, a1.w};
        float b[8] = {b0.x, b0.y, b0.z, b0.w, b1.x, b1.y, b1.z, b1.w};
        #pragma unroll
        for (int i = 0; i < 8; ++i)
            #pragma unroll
            for (int j = 0; j < 8; ++j) acc[i][j] += a[i] * b[j];
    }
    float4 t0 = *(const float4*)(dtb + bn + tn);
    float4 t1 = *(const float4*)(dtb + bn + tn + 4);
    float bias[8] = {t0.x, t0.y, t0.z, t0.w, t1.x, t1.y, t1.z, t1.w};
    #pragma unroll
    for (int i = 0; i < 8; ++i) {
        ushort_t o16[8];
        #pragma unroll
        for (int j = 0; j < 8; ++j) {
            float v = acc[i][j] + bias[j];
            v = (v > 20.f) ? v : __logf(1.f + __expf(v));
            o16[j] = f2h(v);
        }
        size_t off = (size_t)(bm + tm + i) * ED + bn + tn;  // tn%8==0 -> 16B aligned
        *(uint4*)(dyh + off) = *(uint4*)o16;
    }
}

// ================ chunked selective scan (CS=16, NC=64) ================
__global__ __launch_bounds__(256) void k_scan1(const ushort_t* __restrict__ dyh,
                                               const float* __restrict__ u,
                                               const float* __restrict__ xdb,
                                               const float* __restrict__ A_log,
                                               float* __restrict__ P,
                                               float* __restrict__ S) {
    int tid = threadIdx.x;
    int e = ((blockIdx.x & 3) << 8) + tid;
    int c = (blockIdx.x >> 2) & (NC - 1);
    int b = blockIdx.x >> 8;              // 2 bits e-group + 6 bits chunk
    float Ac[16];
    const float4* ap = (const float4*)(A_log + (size_t)e * NST);
    #pragma unroll
    for (int q = 0; q < 4; ++q) {
        float4 a = ap[q];
        Ac[q * 4 + 0] = -__expf(a.x); Ac[q * 4 + 1] = -__expf(a.y);
        Ac[q * 4 + 2] = -__expf(a.z); Ac[q * 4 + 3] = -__expf(a.w);
    }
    float h[16] = {};
    float s = 0.f;
    const ushort_t* dp = dyh + ((size_t)b * LL + c * CS) * ED + e;
    const float* up = u + ((size_t)b * LL + c * CS) * ED + e;
    const float* xp = xdb + ((size_t)b * LL + c * CS) * XDBC;
    for (int tt = 0; tt < CS; ++tt) {
        float dv = h2f(dp[(size_t)tt * ED]);
        float uv = up[(size_t)tt * ED];
        s += dv;
        float du = dv * uv;
        const float4* bp = (const float4*)(xp + tt * XDBC + DTR);
        #pragma unroll
        for (int q = 0; q < 4; ++q) {
            float4 bv = bp[q];
            h[q * 4 + 0] = __expf(dv * Ac[q * 4 + 0]) * h[q * 4 + 0] + du * bv.x;
            h[q * 4 + 1] = __expf(dv * Ac[q * 4 + 1]) * h[q * 4 + 1] + du * bv.y;
            h[q * 4 + 2] = __expf(dv * Ac[q * 4 + 2]) * h[q * 4 + 2] + du * bv.z;
            h[q * 4 + 3] = __expf(dv * Ac[q * 4 + 3]) * h[q * 4 + 3] + du * bv.w;
        }
    }
    float4* pp = (float4*)(P + ((size_t)(b * NC + c) * ED + e) * NST);
    pp[0] = make_float4(h[0], h[1], h[2], h[3]);
    pp[1] = make_float4(h[4], h[5], h[6], h[7]);
    pp[2] = make_float4(h[8], h[9], h[10], h[11]);
    pp[3] = make_float4(h[12], h[13], h[14], h[15]);
    S[(size_t)(b * NC + c) * ED + e] = s;
}

__global__ __launch_bounds__(256) void k_scan2(float* __restrict__ P,
                                               const float* __restrict__ S,
                                               const float* __restrict__ A_log) {
    int i = blockIdx.x * 256 + threadIdx.x;
    int n = i & 15;
    int e = (i >> 4) & (ED - 1);
    int b = i >> 14;
    float Ac = -__expf(A_log[(size_t)e * NST + n]);
    float hin = 0.f;
    for (int c = 0; c < NC; ++c) {
        size_t base = (size_t)(b * NC + c) * ED + e;
        float p = P[base * NST + n];
        float s = S[base];
        P[base * NST + n] = hin;
        hin = __expf(Ac * s) * hin + p;
    }
}

// Pass 3: re-scan with correct h_in; fused silu(z) gate (bf16 z); bf16 yb out.
__global__ __launch_bounds__(256) void k_scan3(const ushort_t* __restrict__ dyh,
                                               const float* __restrict__ u,
                                               const float* __restrict__ xdb,
                                               const ushort_t* __restrict__ xzb,
                                               const float* __restrict__ A_log,
                                               const float* __restrict__ Dskip,
                                               const float* __restrict__ P,
                                               ushort_t* __restrict__ yb) {
    int tid = threadIdx.x;
    int e = ((blockIdx.x & 3) << 8) + tid;
    int c = (blockIdx.x >> 2) & (NC - 1);
    int b = blockIdx.x >> 8;
    float Ac[16], h[16];
    const float4* ap = (const float4*)(A_log + (size_t)e * NST);
    #pragma unroll
    for (int q = 0; q < 4; ++q) {
        float4 a = ap[q];
        Ac[q * 4 + 0] = -__expf(a.x); Ac[q * 4 + 1] = -__expf(a.y);
        Ac[q * 4 + 2] = -__expf(a.z); Ac[q * 4 + 3] = -__expf(a.w);
    }
    const float4* pp = (const float4*)(P + ((size_t)(b * NC + c) * ED + e) * NST);
    #pragma unroll
    for (int q = 0; q < 4; ++q) {
        float4 hv = pp[q];
        h[q * 4 + 0] = hv.x; h[q * 4 + 1] = hv.y;
        h[q * 4 + 2] = hv.z; h[q * 4 + 3] = hv.w;
    }
    float Dk = Dskip[e];
    const ushort_t* dp = dyh + ((size_t)b * LL + c * CS) * ED + e;
    const float* up = u + ((size_t)b * LL + c * CS) * ED + e;
    const float* xp = xdb + ((size_t)b * LL + c * CS) * XDBC;
    const ushort_t* zp = xzb + ((size_t)b * LL + c * CS) * 2048 + 1024 + e;
    ushort_t* yp = yb + ((size_t)b * LL + c * CS) * ED + e;
    for (int tt = 0; tt < CS; ++tt) {
        float dv = h2f(dp[(size_t)tt * ED]);
        float uv = up[(size_t)tt * ED];
        float zv = b2f(zp[(size_t)tt * 2048]);
        float du = dv * uv;
        const float4* bp = (const float4*)(xp + tt * XDBC + DTR);
        const float4* cp = (const float4*)(xp + tt * XDBC + DTR + NST);
        float y = 0.f;
        #pragma unroll
        for (int q = 0; q < 4; ++q) {
            float4 bv = bp[q];
            float4 cv = cp[q];
            h[q * 4 + 0] = __expf(dv * Ac[q * 4 + 0]) * h[q * 4 + 0] + du * bv.x;
            h[q * 4 + 1] = __expf(dv * Ac[q * 4 + 1]) * h[q * 4 + 1] + du * bv.y;
            h[q * 4 + 2] = __expf(dv * Ac[q * 4 + 2]) * h[q * 4 + 2] + du * bv.z;
            h[q * 4 + 3] = __expf(dv * Ac[q * 4 + 3]) * h[q * 4 + 3] + du * bv.w;
            y += h[q * 4 + 0] * cv.x + h[q * 4 + 1] * cv.y +
                 h[q * 4 + 2] * cv.z + h[q * 4 + 3] * cv.w;
        }
        yp[(size_t)tt * ED] = f2b((y + Dk * uv) * silu_f(zv));
    }
}

extern "C" void kernel_launch(void* const* d_in, const int* in_sizes, int n_in,
                              void* d_out, int out_size, void* d_ws, size_t ws_size,
                              hipStream_t stream) {
    const float* x     = (const float*)d_in[0];
    const float* embW  = (const float*)d_in[1];
    const float* embB  = (const float*)d_in[2];
    const float* normw = (const float*)d_in[3];
    const float* ipW   = (const float*)d_in[4];
    const float* cW    = (const float*)d_in[5];
    const float* cb    = (const float*)d_in[6];
    const float* xpW   = (const float*)d_in[7];
    const float* dtW   = (const float*)d_in[8];
    const float* dtb   = (const float*)d_in[9];
    const float* Alog  = (const float*)d_in[10];
    const float* Dsk   = (const float*)d_in[11];
    const float* opW   = (const float*)d_in[12];
    const float* normfw= (const float*)d_in[13];
    float* out = (float*)d_out;

    // ws: h 8 | xzb 16 | u 16 | xdb 1 | Pp/P 16 (aliased: xproj->xred vs
    // scan1->scan3, disjoint) | S 1 | wip 4 | wop 2 | yb 8  = 72 MB.
    // d_out (8 MB) triple-duty per layer: bf16 rmsnorm scratch (rmsnorm->bgemm0),
    // then fp16 delta (k_delta->scan3); final rmsnorm rewrites it entirely.
    float* ws  = (float*)d_ws;
    float* h   = ws;
    ushort_t* xzb = (ushort_t*)(h + (size_t)BL * DM);
    float* u   = (float*)(xzb + (size_t)BL * 2 * ED);
    float* xdb = u + (size_t)BL * ED;
    float* Pp  = xdb + (size_t)BL * XDBC;                   // 4M floats
    float* S   = Pp + (size_t)BL * ED;                      // BB*NC*ED = 256K
    ushort_t* wip = (ushort_t*)(S + (size_t)BB * NC * ED);
    ushort_t* wop = wip + (size_t)2 * 2 * ED * DM;
    ushort_t* yb  = wop + (size_t)2 * DM * ED;
    float* P      = Pp;                 // chunk-state buffer aliases Pp
    ushort_t* hnb = (ushort_t*)d_out;   // bf16 rmsnorm scratch
    ushort_t* dyh = (ushort_t*)d_out;   // fp16 delta (later phase, same mem)

    k_embed<<<(BL * DM + 255) / 256, 256, 0, stream>>>(x, embW, embB, h);
    k_cvt<<<(2 * 2 * ED * DM / 4 + 255) / 256, 256, 0, stream>>>(ipW, wip, 2 * 2 * ED * DM / 4);
    k_cvt<<<(2 * DM * ED / 4 + 255) / 256, 256, 0, stream>>>(opW, wop, 2 * DM * ED / 4);

    for (int l = 0; l < 2; ++l) {
        const float* Al = Alog + (size_t)l * ED * NST;
        k_rmsnorm<1><<<BL, 256, 0, stream>>>(h, normw + (size_t)l * DM, hnb);
        k_bgemm<0, 1><<<dim3(2 * ED / 128, BL / 128), 256, 0, stream>>>(
            hnb, wip + (size_t)l * 2 * ED * DM, nullptr, xzb, BL, 2 * ED, DM, DM, 2 * ED);
        k_conv<<<(BL * ED + 255) / 256, 256, 0, stream>>>(
            xzb, cW + (size_t)l * ED * 4, cb + (size_t)l * ED, u);
        k_xproj<<<dim3(XKS, BL / 64), 256, 0, stream>>>(
            u, xpW + (size_t)l * XDBC * ED, Pp);
        k_xred<<<BL * XDBC / 4 / 256, 256, 0, stream>>>(Pp, xdb);
        k_delta<<<dim3(ED / 128, BL / 128), 256, 0, stream>>>(
            xdb, dtW + (size_t)l * ED * DTR, dtb + (size_t)l * ED, dyh);
        k_scan1<<<BB * NC * (ED / 256), 256, 0, stream>>>(dyh, u, xdb, Al, P, S);
        k_scan2<<<BB * ED * NST / 256, 256, 0, stream>>>(P, S, Al);
        k_scan3<<<BB * NC * (ED / 256), 256, 0, stream>>>(
            dyh, u, xdb, xzb, Al, Dsk + (size_t)l * ED, P, yb);
        k_bgemm<1, 0><<<dim3(DM / 128, BL / 128), 256, 0, stream>>>(
            yb, wop + (size_t)l * DM * ED, h, h, BL, DM, ED, ED, DM);
    }
    k_rmsnorm<0><<<BL, 256, 0, stream>>>(h, normfw, out);
}

// Round 12
// 297.283 us; speedup vs baseline: 1.1538x; 1.0071x over previous
//
#include <hip/hip_runtime.h>
#include <math.h>
#include <stddef.h>

#define BB 4
#define LL 1024
#define DM 512
#define ED 1024
#define NST 16
#define DTR 32
#define XDBC 64
#define BL (BB*LL)   // 4096
#define CS 16        // scan chunk length
#define NC 64        // chunks per sequence (LL/CS)
#define XKS 16       // x_proj K-slices
#define XPAD 68      // x_proj LDS stride (floats)
#define DPAD 132     // k_delta LDS stride (floats)

typedef __attribute__((ext_vector_type(8))) short bf16x8;
typedef __attribute__((ext_vector_type(4))) float f32x4;
typedef unsigned short ushort_t;

__device__ __forceinline__ float silu_f(float x) { return x / (1.f + __expf(-x)); }

__device__ __forceinline__ ushort_t f2b(float f) {
    unsigned int u = __float_as_uint(f);
    unsigned int r = (u + 0x7FFFu + ((u >> 16) & 1u)) >> 16;
    return (ushort_t)r;
}
__device__ __forceinline__ float b2f(ushort_t v) {
    return __uint_as_float(((unsigned int)v) << 16);
}
__device__ __forceinline__ ushort_t f2h(float f) {
    _Float16 h = (_Float16)f;
    return *(ushort_t*)&h;
}
__device__ __forceinline__ float h2f(ushort_t v) {
    _Float16 h = *(_Float16*)&v;
    return (float)h;
}

// async global->LDS, 16B per lane; LDS dest = wave-uniform base + lane*16
__device__ __forceinline__ void gload16(const ushort_t* g, ushort_t* l) {
    __builtin_amdgcn_global_load_lds(
        (const __attribute__((address_space(1))) unsigned int*)g,
        (__attribute__((address_space(3))) unsigned int*)l, 16, 0, 0);
}

// ---------------- embedding
__global__ void k_embed(const float* __restrict__ x, const float* __restrict__ W,
                        const float* __restrict__ bias, float* __restrict__ h) {
    int i = blockIdx.x * 256 + threadIdx.x;
    if (i >= BL * DM) return;
    int d = i % DM, r = i / DM;
    h[i] = x[r * 2 + 0] * W[d * 2 + 0] + x[r * 2 + 1] * W[d * 2 + 1] + bias[d];
}

// ---------------- both weight arrays fp32 -> bf16 in one dispatch
__global__ void k_cvt2(const float* __restrict__ ip, const float* __restrict__ op,
                       ushort_t* __restrict__ wip, ushort_t* __restrict__ wop,
                       int n1, int n2) {
    int i = blockIdx.x * 256 + threadIdx.x;
    const float* src; ushort_t* dst; int q;
    if (i < n1) { src = ip; dst = wip; q = i; }
    else if (i < n1 + n2) { src = op; dst = wop; q = i - n1; }
    else return;
    float4 v = *(const float4*)(src + (size_t)q * 4);
    ushort_t o[4] = {f2b(v.x), f2b(v.y), f2b(v.z), f2b(v.w)};
    *(uint2*)(dst + (size_t)q * 4) = *(uint2*)o;
}

// ---------------- rmsnorm over rows of 512; BF16OUT selects output dtype
template <int BF16OUT>
__global__ __launch_bounds__(256) void k_rmsnorm(const float* __restrict__ in,
                                                 const float* __restrict__ w,
                                                 void* __restrict__ outp) {
    int m = blockIdx.x;
    int tid = threadIdx.x;
    const float* row = in + (size_t)m * DM;
    float2 v = *(const float2*)(row + tid * 2);
    float ss = v.x * v.x + v.y * v.y;
    #pragma unroll
    for (int o = 32; o > 0; o >>= 1) ss += __shfl_down(ss, o, 64);
    __shared__ float red[4];
    int wid = tid >> 6;
    if ((tid & 63) == 0) red[wid] = ss;
    __syncthreads();
    float tot = red[0] + red[1] + red[2] + red[3];
    float rs = rsqrtf(tot * (1.f / DM) + 1e-5f);
    float2 wv = *(const float2*)(w + tid * 2);
    float ox = v.x * rs * wv.x;
    float oy = v.y * rs * wv.y;
    if (BF16OUT) {
        ushort_t o[2] = {f2b(ox), f2b(oy)};
        *(unsigned int*)((ushort_t*)outp + (size_t)m * DM + tid * 2) = *(unsigned int*)o;
    } else {
        *(float2*)((float*)outp + (size_t)m * DM + tid * 2) = make_float2(ox, oy);
    }
}

// ---------------- bf16 MFMA GEMM with global_load_lds staging.
// Tile 128 x NT, 4 waves (2x2), BK=32. LDS linear [rows][32] ushorts with
// chunk swizzle c ^= (row>>1)&3 applied on SOURCE addr and on ds_read addr
// (linear dest + inverse-swz source + swz read — both-sides-or-neither).
template <int ADDRES, int BF16OUT, int NT>
__global__ __launch_bounds__(256) void k_bgemm(const ushort_t* __restrict__ A,
                                               const ushort_t* __restrict__ W,
                                               const float* __restrict__ Res,
                                               void* __restrict__ C,
                                               int M, int N, int K, int lda, int ldc) {
    __shared__ ushort_t As[128 * 32];
    __shared__ ushort_t Bs[NT * 32];
    constexpr int NFJ = NT / 32;              // col fragments per wave
    int tid = threadIdx.x;
    int bm = blockIdx.y * 128, bn = blockIdx.x * NT;
    int wave = tid >> 6, lane = tid & 63;
    int wr = wave >> 1, wc = wave & 1;
    int lr = lane & 15;
    int kc = lane >> 4;                       // k-chunk 0..3
    f32x4 acc[4][NFJ];
    #pragma unroll
    for (int i = 0; i < 4; ++i)
        #pragma unroll
        for (int j = 0; j < NFJ; ++j) acc[i][j] = (f32x4){0.f, 0.f, 0.f, 0.f};

    for (int k0 = 0; k0 < K; k0 += 32) {
        __syncthreads();                      // prior reads done before overwrite
        // A tile: 128 rows x 4 chunks = 512 chunks = 8 issues; 2 per wave
        #pragma unroll
        for (int ii = 0; ii < 2; ++ii) {
            int g = wave * 128 + ii * 64 + lane;
            int row = g >> 2;
            int c = (g & 3) ^ ((g >> 3) & 3);
            gload16(A + (size_t)(bm + row) * lda + k0 + c * 8,
                    As + (size_t)(wave * 128 + ii * 64) * 8);
        }
        // B tile: NT*4 chunks; NFJ/2 issues per wave
        #pragma unroll
        for (int ii = 0; ii < NFJ / 2; ++ii) {
            int g = wave * (NFJ / 2) * 64 + ii * 64 + lane;
            int row = g >> 2;
            int c = (g & 3) ^ ((g >> 3) & 3);
            gload16(W + (size_t)(bn + row) * K + k0 + c * 8,
                    Bs + (size_t)(wave * (NFJ / 2) * 64 + ii * 64) * 8);
        }
        __syncthreads();                      // drains vmcnt -> LDS ready
        bf16x8 af[4], bfr[NFJ];
        #pragma unroll
        for (int i = 0; i < 4; ++i) {
            int ra = wr * 64 + i * 16 + lr;
            int ca = kc ^ ((ra >> 1) & 3);
            af[i] = *(const bf16x8*)(As + ra * 32 + ca * 8);
        }
        #pragma unroll
        for (int j = 0; j < NFJ; ++j) {
            int rb = wc * (NT / 2) + j * 16 + lr;
            int cb = kc ^ ((rb >> 1) & 3);
            bfr[j] = *(const bf16x8*)(Bs + rb * 32 + cb * 8);
        }
        #pragma unroll
        for (int i = 0; i < 4; ++i)
            #pragma unroll
            for (int j = 0; j < NFJ; ++j)
                acc[i][j] = __builtin_amdgcn_mfma_f32_16x16x32_bf16(af[i], bfr[j], acc[i][j], 0, 0, 0);
    }
    int crow0 = bm + wr * 64 + (lane >> 4) * 4;
    #pragma unroll
    for (int i = 0; i < 4; ++i)
        #pragma unroll
        for (int j = 0; j < NFJ; ++j)
            #pragma unroll
            for (int r = 0; r < 4; ++r) {
                size_t off = (size_t)(crow0 + i * 16 + r) * ldc + bn + wc * (NT / 2) + j * 16 + lr;
                float v = acc[i][j][r];
                if (ADDRES) v += Res[off];
                if (BF16OUT) ((ushort_t*)C)[off] = f2b(v);
                else         ((float*)C)[off] = v;
            }
}

// ---------------- x_proj split-K; u is bf16 now
__global__ __launch_bounds__(256) void k_xproj(const ushort_t* __restrict__ A,
                                               const float* __restrict__ W,
                                               float* __restrict__ Pp) {
    __shared__ float As[64][XPAD];
    __shared__ float Ws[64][XPAD];
    int tid = threadIdx.x;
    int k0 = blockIdx.x * 64;
    int bm = blockIdx.y * 64;
    int r = tid >> 2;
    int kc = (tid & 3) * 16;
    const ushort_t* ap = A + (size_t)(bm + r) * ED + k0 + kc;
    const float4* wp = (const float4*)(W + (size_t)r * ED + k0 + kc);
    uint4 a0 = *(const uint4*)(ap);
    uint4 a1 = *(const uint4*)(ap + 8);
    const ushort_t* pa0 = (const ushort_t*)&a0;
    const ushort_t* pa1 = (const ushort_t*)&a1;
    #pragma unroll
    for (int i = 0; i < 8; ++i) {
        As[kc + i][r] = b2f(pa0[i]);
        As[kc + 8 + i][r] = b2f(pa1[i]);
    }
    #pragma unroll
    for (int i = 0; i < 4; ++i) {
        float4 wv = wp[i];
        Ws[kc + i * 4 + 0][r] = wv.x; Ws[kc + i * 4 + 1][r] = wv.y;
        Ws[kc + i * 4 + 2][r] = wv.z; Ws[kc + i * 4 + 3][r] = wv.w;
    }
    __syncthreads();
    int tm = (tid >> 4) * 4;
    int tn = (tid & 15) * 4;
    float acc[4][4] = {};
    #pragma unroll 4
    for (int k = 0; k < 64; ++k) {
        float4 a = *(const float4*)&As[k][tm];
        float4 b = *(const float4*)&Ws[k][tn];
        acc[0][0] += a.x * b.x; acc[0][1] += a.x * b.y; acc[0][2] += a.x * b.z; acc[0][3] += a.x * b.w;
        acc[1][0] += a.y * b.x; acc[1][1] += a.y * b.y; acc[1][2] += a.y * b.z; acc[1][3] += a.y * b.w;
        acc[2][0] += a.z * b.x; acc[2][1] += a.z * b.y; acc[2][2] += a.z * b.z; acc[2][3] += a.z * b.w;
        acc[3][0] += a.w * b.x; acc[3][1] += a.w * b.y; acc[3][2] += a.w * b.z; acc[3][3] += a.w * b.w;
    }
    float* pp = Pp + (size_t)blockIdx.x * BL * XDBC;
    #pragma unroll
    for (int i = 0; i < 4; ++i)
        *(float4*)(pp + (size_t)(bm + tm + i) * XDBC + tn) =
            make_float4(acc[i][0], acc[i][1], acc[i][2], acc[i][3]);
}

// reduce 16 K-slice partials -> xdb
__global__ void k_xred(const float* __restrict__ Pp, float* __restrict__ xdb) {
    int i = blockIdx.x * 256 + threadIdx.x;
    float4 s = make_float4(0.f, 0.f, 0.f, 0.f);
    #pragma unroll
    for (int sl = 0; sl < XKS; ++sl) {
        float4 v = *(const float4*)(Pp + (size_t)sl * BL * XDBC + (size_t)i * 4);
        s.x += v.x; s.y += v.y; s.z += v.z; s.w += v.w;
    }
    *(float4*)(xdb + (size_t)i * 4) = s;
}

// ---------------- causal depthwise conv (k=4) + bias + silu; bf16 in/out
__global__ void k_conv(const ushort_t* __restrict__ xzb, const float* __restrict__ cw,
                       const float* __restrict__ cb, ushort_t* __restrict__ u) {
    int i = blockIdx.x * 256 + threadIdx.x;
    if (i >= BL * ED) return;
    int e = i % ED;
    int t = (i / ED) % LL;
    int b = i / (ED * LL);
    const ushort_t* col = xzb + (size_t)b * LL * 2048 + e;
    float4 w4 = *(const float4*)(cw + e * 4);
    float acc = cb[e];
    if (t >= 3) acc += b2f(col[(size_t)(t - 3) * 2048]) * w4.x;
    if (t >= 2) acc += b2f(col[(size_t)(t - 2) * 2048]) * w4.y;
    if (t >= 1) acc += b2f(col[(size_t)(t - 1) * 2048]) * w4.z;
    acc += b2f(col[(size_t)t * 2048]) * w4.w;
    u[i] = f2b(silu_f(acc));
}

// ---------------- delta = softplus(dt @ dtW^T + dtb), tiled; fp16 output
__global__ __launch_bounds__(256) void k_delta(const float* __restrict__ xdb,
                                               const float* __restrict__ dtW,
                                               const float* __restrict__ dtb,
                                               ushort_t* __restrict__ dyh) {
    __shared__ float Dt[32][DPAD];
    __shared__ float Wt[32][DPAD];
    int tid = threadIdx.x;
    int bm = blockIdx.y * 128;
    int bn = blockIdx.x * 128;
    int r = tid >> 1;
    int hh = (tid & 1) * 16;
    const float4* dp = (const float4*)(xdb + (size_t)(bm + r) * XDBC + hh);
    const float4* wp = (const float4*)(dtW + (size_t)(bn + r) * 32 + hh);
    #pragma unroll
    for (int i = 0; i < 4; ++i) {
        float4 v = dp[i];
        Dt[hh + i * 4 + 0][r] = v.x; Dt[hh + i * 4 + 1][r] = v.y;
        Dt[hh + i * 4 + 2][r] = v.z; Dt[hh + i * 4 + 3][r] = v.w;
        float4 w = wp[i];
        Wt[hh + i * 4 + 0][r] = w.x; Wt[hh + i * 4 + 1][r] = w.y;
        Wt[hh + i * 4 + 2][r] = w.z; Wt[hh + i * 4 + 3][r] = w.w;
    }
    __syncthreads();
    int tm = (tid >> 4) * 8;
    int tn = (tid & 15) * 8;
    float acc[8][8] = {};
    #pragma unroll 8
    for (int k = 0; k < 32; ++k) {
        float4 a0 = *(const float4*)&Dt[k][tm];
        float4 a1 = *(const float4*)&Dt[k][tm + 4];
        float4 b0 = *(const float4*)&Wt[k][tn];
        float4 b1 = *(const float4*)&Wt[k][tn + 4];
        float a[8] = {a0.x, a0.y, a0.z, a0.w, a1.x, a1.y, a1.z, a1.w};
        float b[8] = {b0.x, b0.y, b0.z, b0.w, b1.x, b1.y, b1.z, b1.w};
        #pragma unroll
        for (int i = 0; i < 8; ++i)
            #pragma unroll
            for (int j = 0; j < 8; ++j) acc[i][j] += a[i] * b[j];
    }
    float4 t0 = *(const float4*)(dtb + bn + tn);
    float4 t1 = *(const float4*)(dtb + bn + tn + 4);
    float bias[8] = {t0.x, t0.y, t0.z, t0.w, t1.x, t1.y, t1.z, t1.w};
    #pragma unroll
    for (int i = 0; i < 8; ++i) {
        ushort_t o16[8];
        #pragma unroll
        for (int j = 0; j < 8; ++j) {
            float v = acc[i][j] + bias[j];
            v = (v > 20.f) ? v : __logf(1.f + __expf(v));
            o16[j] = f2h(v);
        }
        size_t off = (size_t)(bm + tm + i) * ED + bn + tn;
        *(uint4*)(dyh + off) = *(uint4*)o16;
    }
}

// ================ chunked selective scan (CS=16, NC=64) ================
__global__ __launch_bounds__(256) void k_scan1(const ushort_t* __restrict__ dyh,
                                               const ushort_t* __restrict__ u,
                                               const float* __restrict__ xdb,
                                               const float* __restrict__ A_log,
                                               float* __restrict__ P,
                                               float* __restrict__ S) {
    int tid = threadIdx.x;
    int e = ((blockIdx.x & 3) << 8) + tid;
    int c = (blockIdx.x >> 2) & (NC - 1);
    int b = blockIdx.x >> 8;
    float Ac[16];
    const float4* ap = (const float4*)(A_log + (size_t)e * NST);
    #pragma unroll
    for (int q = 0; q < 4; ++q) {
        float4 a = ap[q];
        Ac[q * 4 + 0] = -__expf(a.x); Ac[q * 4 + 1] = -__expf(a.y);
        Ac[q * 4 + 2] = -__expf(a.z); Ac[q * 4 + 3] = -__expf(a.w);
    }
    float h[16] = {};
    float s = 0.f;
    const ushort_t* dp = dyh + ((size_t)b * LL + c * CS) * ED + e;
    const ushort_t* up = u + ((size_t)b * LL + c * CS) * ED + e;
    const float* xp = xdb + ((size_t)b * LL + c * CS) * XDBC;
    for (int tt = 0; tt < CS; ++tt) {
        float dv = h2f(dp[(size_t)tt * ED]);
        float uv = b2f(up[(size_t)tt * ED]);
        s += dv;
        float du = dv * uv;
        const float4* bp = (const float4*)(xp + tt * XDBC + DTR);
        #pragma unroll
        for (int q = 0; q < 4; ++q) {
            float4 bv = bp[q];
            h[q * 4 + 0] = __expf(dv * Ac[q * 4 + 0]) * h[q * 4 + 0] + du * bv.x;
            h[q * 4 + 1] = __expf(dv * Ac[q * 4 + 1]) * h[q * 4 + 1] + du * bv.y;
            h[q * 4 + 2] = __expf(dv * Ac[q * 4 + 2]) * h[q * 4 + 2] + du * bv.z;
            h[q * 4 + 3] = __expf(dv * Ac[q * 4 + 3]) * h[q * 4 + 3] + du * bv.w;
        }
    }
    float4* pp = (float4*)(P + ((size_t)(b * NC + c) * ED + e) * NST);
    pp[0] = make_float4(h[0], h[1], h[2], h[3]);
    pp[1] = make_float4(h[4], h[5], h[6], h[7]);
    pp[2] = make_float4(h[8], h[9], h[10], h[11]);
    pp[3] = make_float4(h[12], h[13], h[14], h[15]);
    S[(size_t)(b * NC + c) * ED + e] = s;
}

__global__ __launch_bounds__(256) void k_scan2(float* __restrict__ P,
                                               const float* __restrict__ S,
                                               const float* __restrict__ A_log) {
    int i = blockIdx.x * 256 + threadIdx.x;
    int n = i & 15;
    int e = (i >> 4) & (ED - 1);
    int b = i >> 14;
    float Ac = -__expf(A_log[(size_t)e * NST + n]);
    float hin = 0.f;
    for (int c = 0; c < NC; ++c) {
        size_t base = (size_t)(b * NC + c) * ED + e;
        float p = P[base * NST + n];
        float s = S[base];
        P[base * NST + n] = hin;
        hin = __expf(Ac * s) * hin + p;
    }
}

// Pass 3: re-scan with h_in; fused silu(z) gate; bf16 yb out.
__global__ __launch_bounds__(256) void k_scan3(const ushort_t* __restrict__ dyh,
                                               const ushort_t* __restrict__ u,
                                               const float* __restrict__ xdb,
                                               const ushort_t* __restrict__ xzb,
                                               const float* __restrict__ A_log,
                                               const float* __restrict__ Dskip,
                                               const float* __restrict__ P,
                                               ushort_t* __restrict__ yb) {
    int tid = threadIdx.x;
    int e = ((blockIdx.x & 3) << 8) + tid;
    int c = (blockIdx.x >> 2) & (NC - 1);
    int b = blockIdx.x >> 8;
    float Ac[16], h[16];
    const float4* ap = (const float4*)(A_log + (size_t)e * NST);
    #pragma unroll
    for (int q = 0; q < 4; ++q) {
        float4 a = ap[q];
        Ac[q * 4 + 0] = -__expf(a.x); Ac[q * 4 + 1] = -__expf(a.y);
        Ac[q * 4 + 2] = -__expf(a.z); Ac[q * 4 + 3] = -__expf(a.w);
    }
    const float4* pp = (const float4*)(P + ((size_t)(b * NC + c) * ED + e) * NST);
    #pragma unroll
    for (int q = 0; q < 4; ++q) {
        float4 hv = pp[q];
        h[q * 4 + 0] = hv.x; h[q * 4 + 1] = hv.y;
        h[q * 4 + 2] = hv.z; h[q * 4 + 3] = hv.w;
    }
    float Dk = Dskip[e];
    const ushort_t* dp = dyh + ((size_t)b * LL + c * CS) * ED + e;
    const ushort_t* up = u + ((size_t)b * LL + c * CS) * ED + e;
    const float* xp = xdb + ((size_t)b * LL + c * CS) * XDBC;
    const ushort_t* zp = xzb + ((size_t)b * LL + c * CS) * 2048 + 1024 + e;
    ushort_t* yp = yb + ((size_t)b * LL + c * CS) * ED + e;
    for (int tt = 0; tt < CS; ++tt) {
        float dv = h2f(dp[(size_t)tt * ED]);
        float uv = b2f(up[(size_t)tt * ED]);
        float zv = b2f(zp[(size_t)tt * 2048]);
        float du = dv * uv;
        const float4* bp = (const float4*)(xp + tt * XDBC + DTR);
        const float4* cp = (const float4*)(xp + tt * XDBC + DTR + NST);
        float y = 0.f;
        #pragma unroll
        for (int q = 0; q < 4; ++q) {
            float4 bv = bp[q];
            float4 cv = cp[q];
            h[q * 4 + 0] = __expf(dv * Ac[q * 4 + 0]) * h[q * 4 + 0] + du * bv.x;
            h[q * 4 + 1] = __expf(dv * Ac[q * 4 + 1]) * h[q * 4 + 1] + du * bv.y;
            h[q * 4 + 2] = __expf(dv * Ac[q * 4 + 2]) * h[q * 4 + 2] + du * bv.z;
            h[q * 4 + 3] = __expf(dv * Ac[q * 4 + 3]) * h[q * 4 + 3] + du * bv.w;
            y += h[q * 4 + 0] * cv.x + h[q * 4 + 1] * cv.y +
                 h[q * 4 + 2] * cv.z + h[q * 4 + 3] * cv.w;
        }
        yp[(size_t)tt * ED] = f2b((y + Dk * uv) * silu_f(zv));
    }
}

extern "C" void kernel_launch(void* const* d_in, const int* in_sizes, int n_in,
                              void* d_out, int out_size, void* d_ws, size_t ws_size,
                              hipStream_t stream) {
    const float* x     = (const float*)d_in[0];
    const float* embW  = (const float*)d_in[1];
    const float* embB  = (const float*)d_in[2];
    const float* normw = (const float*)d_in[3];
    const float* ipW   = (const float*)d_in[4];
    const float* cW    = (const float*)d_in[5];
    const float* cb    = (const float*)d_in[6];
    const float* xpW   = (const float*)d_in[7];
    const float* dtW   = (const float*)d_in[8];
    const float* dtb   = (const float*)d_in[9];
    const float* Alog  = (const float*)d_in[10];
    const float* Dsk   = (const float*)d_in[11];
    const float* opW   = (const float*)d_in[12];
    const float* normfw= (const float*)d_in[13];
    float* out = (float*)d_out;

    // ws: h 8MB | xzb 16 | ub 8 | xdb 1 | Pp/P 16 (aliased, disjoint phases)
    //     | S 1 | wip 4 | wop 2 | yb 8  = 64 MB
    float* ws  = (float*)d_ws;
    float* h   = ws;
    ushort_t* xzb = (ushort_t*)(h + (size_t)BL * DM);
    ushort_t* ub  = xzb + (size_t)BL * 2 * ED;
    float* xdb = (float*)(ub + (size_t)BL * ED);
    float* Pp  = xdb + (size_t)BL * XDBC;
    float* S   = Pp + (size_t)XKS * BL * XDBC;
    ushort_t* wip = (ushort_t*)(S + (size_t)BB * NC * ED);
    ushort_t* wop = wip + (size_t)2 * 2 * ED * DM;
    ushort_t* yb  = wop + (size_t)2 * DM * ED;
    float* P      = Pp;                 // chunk-state buffer aliases Pp
    ushort_t* hnb = (ushort_t*)d_out;   // bf16 rmsnorm scratch
    ushort_t* dyh = (ushort_t*)d_out;   // fp16 delta (later phase, same mem)

    k_embed<<<(BL * DM + 255) / 256, 256, 0, stream>>>(x, embW, embB, h);
    int n1 = 2 * 2 * ED * DM / 4, n2 = 2 * DM * ED / 4;
    k_cvt2<<<(n1 + n2 + 255) / 256, 256, 0, stream>>>(ipW, opW, wip, wop, n1, n2);

    for (int l = 0; l < 2; ++l) {
        const float* Al = Alog + (size_t)l * ED * NST;
        k_rmsnorm<1><<<BL, 256, 0, stream>>>(h, normw + (size_t)l * DM, hnb);
        k_bgemm<0, 1, 128><<<dim3(2 * ED / 128, BL / 128), 256, 0, stream>>>(
            hnb, wip + (size_t)l * 2 * ED * DM, nullptr, xzb, BL, 2 * ED, DM, DM, 2 * ED);
        k_conv<<<(BL * ED + 255) / 256, 256, 0, stream>>>(
            xzb, cW + (size_t)l * ED * 4, cb + (size_t)l * ED, ub);
        k_xproj<<<dim3(XKS, BL / 64), 256, 0, stream>>>(
            ub, xpW + (size_t)l * XDBC * ED, Pp);
        k_xred<<<BL * XDBC / 4 / 256, 256, 0, stream>>>(Pp, xdb);
        k_delta<<<dim3(ED / 128, BL / 128), 256, 0, stream>>>(
            xdb, dtW + (size_t)l * ED * DTR, dtb + (size_t)l * ED, dyh);
        k_scan1<<<BB * NC * (ED / 256), 256, 0, stream>>>(dyh, ub, xdb, Al, P, S);
        k_scan2<<<BB * ED * NST / 256, 256, 0, stream>>>(P, S, Al);
        k_scan3<<<BB * NC * (ED / 256), 256, 0, stream>>>(
            dyh, ub, xdb, xzb, Al, Dsk + (size_t)l * ED, P, yb);
        k_bgemm<1, 0, 64><<<dim3(DM / 64, BL / 128), 256, 0, stream>>>(
            yb, wop + (size_t)l * DM * ED, h, h, BL, DM, ED, ED, DM);
    }
    k_rmsnorm<0><<<BL, 256, 0, stream>>>(h, normfw, out);
}